// Round 12
// baseline (113.095 us; speedup 1.0000x reference)
//
#include <hip/hip_runtime.h>
#include <hip/hip_fp16.h>

typedef _Float16 f16x8 __attribute__((ext_vector_type(8)));
typedef float f32x4 __attribute__((ext_vector_type(4)));

// LeNet C3 connection table: input channel ii feeds CONN[ii][j] with weight[j][ii].
__device__ constexpr int CONN[6][10] = {
    {0, 4, 5, 6, 9, 10, 11, 12, 14, 15},
    {0, 1, 5, 6, 7, 10, 11, 12, 13, 15},
    {0, 1, 2, 6, 7, 8, 11, 13, 14, 15},
    {1, 2, 3, 6, 7, 8, 9, 12, 14, 15},
    {2, 3, 4, 7, 8, 9, 10, 12, 13, 15},
    {3, 4, 5, 8, 9, 10, 11, 13, 14, 15}};

__device__ constexpr int CNT[16] = {3,3,3,3,3,3,4,4,4,4,4,4,4,4,4,6};

__device__ __forceinline__ f16x8 u4_to_h8(uint4 u) { f16x8 r; __builtin_memcpy(&r, &u, 16); return r; }

#define PITCH_DW 130           // dwords per LDS row (260 halves: 256 + 4 halo)
#define PLANE_DW 1576          // 12 rows x 130 + 16 pad; stride % 32 == 8 -> kb 2-way max

// Weight A-panel in MFMA A-fragment order (M=16 channels, K'=320 over 10 MFMAs):
// Wp[(ks*64 + lane)*8 + j] = w_full[ch=lane&15][ii(kb,ks)][r(ks)][kx=j]
//   ks 0..4: ii = 2*kb, r = ks (range A); ks 5..9: ii = 2*kb+1, r = ks-5 (range B)
//   kb==3 or j>4 -> 0 (dummy k-slots)
__global__ void prep_A(const float* __restrict__ w, unsigned short* __restrict__ Wp) {
    int t = blockIdx.x * 256 + threadIdx.x;   // half index 0..5119
    if (t >= 5120) return;
    int j = t & 7, lane = (t >> 3) & 63, ks = t >> 9;
    int ch = lane & 15, kb = lane >> 4;
    float val = 0.f;
    if (kb < 3 && j < 5) {
        int ii = 2 * kb + (ks >= 5 ? 1 : 0);
        int r  = (ks >= 5) ? ks - 5 : ks;
        for (int jj = 0; jj < 10; ++jj)
            if (CONN[ii][jj] == ch) val = w[jj * 150 + ii * 25 + r * 5 + j];
    }
    __half h = __float2half(val);
    unsigned short u; __builtin_memcpy(&u, &h, 2);
    Wp[t] = u;
}

// Block: FULL-WIDTH 256x x 8y tile, 4 waves, 37.76 KB LDS -> 4 blocks/CU
// (16 waves, 50% occupancy; was 3 blocks/37.5%). Page-ordered stores kept
// from R11: at strip-step t the 4 waves cover x [64t, 64t+63].
__global__ __launch_bounds__(256, 4) void c3_mfma(
    const float* __restrict__ x, const unsigned short* __restrict__ Wp,
    const float* __restrict__ bias, float* __restrict__ out)
{
    __shared__ unsigned s_lds[5 * PLANE_DW + 12 * PITCH_DW];   // 37760 B

    const int tid = threadIdx.x;
    // 2048 blocks = 64 n x 32 y-tiles; XCD chunks of 256 = 8 whole images/XCD.
    const int id = (blockIdx.x & 7) * 256 + (blockIdx.x >> 3);
    const int by = id & 31;
    const int n  = id >> 5;
    const int Y0 = by * 8;
    const float* xin = x + (size_t)n * 6 * 65536;

    // ---- stage 6ch x 12row x 256col f32 -> fp16 (18 float4 per thread) ----
    #pragma unroll 3
    for (int it = 0; it < 18; ++it) {
        int i   = tid + it * 256;          // 0..4607
        int c4  = i & 63;                  // float4 column
        int t   = i >> 6;                  // 0..71
        int ch  = t / 12;
        int row = t - ch * 12;
        int gr  = Y0 + row; if (gr > 255) gr = 255;   // OOB rows feed only discarded outputs
        float4 v = *reinterpret_cast<const float4*>(
            xin + (size_t)ch * 65536 + (size_t)gr * 256 + c4 * 4);
        __half2 lo = __floats2half2_rn(v.x, v.y);
        __half2 hi = __floats2half2_rn(v.z, v.w);
        uint2 u; __builtin_memcpy(&u.x, &lo, 4); __builtin_memcpy(&u.y, &hi, 4);
        *reinterpret_cast<uint2*>(&s_lds[ch * PLANE_DW + row * PITCH_DW + c4 * 2]) = u;
    }
    // halo cols 256-259 = zeros (feed only masked x>=252 outputs)
    if (tid < 72) {
        int ch = tid / 12, row = tid - ch * 12;
        *reinterpret_cast<uint2*>(&s_lds[ch * PLANE_DW + row * PITCH_DW + 128]) =
            make_uint2(0u, 0u);
    }
    __syncthreads();

    const int lane = tid & 63;
    const int wv   = tid >> 6;
    const int nn   = lane & 15;   // B-col = x offset within strip; C-col = x
    const int kb   = lane >> 4;   // k-block; C rows = ch = kb*4+q

    // ---- weight A-frags (L2-hot, 16B/lane) ----
    f16x8 W[10];
    const uint4* wp4 = reinterpret_cast<const uint4*>(Wp);
    #pragma unroll
    for (int ks = 0; ks < 10; ++ks) W[ks] = u4_to_h8(wp4[ks * 64 + lane]);

    const int iiA = (kb < 3) ? 2 * kb : 0;             // kb3: dummy (zero weights)
    const unsigned shb = (unsigned)((nn & 1) * 16);    // 16-bit funnel shift

    auto loadf = [&](int dwaddr) -> f16x8 {
        unsigned e0 = s_lds[dwaddr],     e1 = s_lds[dwaddr + 1],
                 e2 = s_lds[dwaddr + 2], e3 = s_lds[dwaddr + 3],
                 e4 = s_lds[dwaddr + 4];
        unsigned o0 = (unsigned)((((unsigned long long)e1 << 32) | e0) >> shb);
        unsigned o1 = (unsigned)((((unsigned long long)e2 << 32) | e1) >> shb);
        unsigned o2 = (unsigned)((((unsigned long long)e3 << 32) | e2) >> shb);
        unsigned o3 = (unsigned)((((unsigned long long)e4 << 32) | e3) >> shb);
        return u4_to_h8(make_uint4(o0, o1, o2, o3));
    };

    float bb[4];
    #pragma unroll
    for (int q = 0; q < 4; ++q) {
        int ch = kb * 4 + q;
        bb[q] = bias[ch] * (float)CNT[ch];
    }

#define PHASE(a0,a1,a2,a3,a4,b0,b1,b2,b3,b4)                                    \
    {                                                                           \
        f32x4 accA = {bb[0], bb[1], bb[2], bb[3]};                              \
        f32x4 accB = {0.f, 0.f, 0.f, 0.f};                                      \
        accA = __builtin_amdgcn_mfma_f32_16x16x32_f16(W[0], a0, accA, 0, 0, 0); \
        accB = __builtin_amdgcn_mfma_f32_16x16x32_f16(W[5], b0, accB, 0, 0, 0); \
        a0 = loadf(aN); b0 = loadf(aN + PLANE_DW); aN += PITCH_DW;              \
        accA = __builtin_amdgcn_mfma_f32_16x16x32_f16(W[1], a1, accA, 0, 0, 0); \
        accB = __builtin_amdgcn_mfma_f32_16x16x32_f16(W[6], b1, accB, 0, 0, 0); \
        accA = __builtin_amdgcn_mfma_f32_16x16x32_f16(W[2], a2, accA, 0, 0, 0); \
        accB = __builtin_amdgcn_mfma_f32_16x16x32_f16(W[7], b2, accB, 0, 0, 0); \
        accA = __builtin_amdgcn_mfma_f32_16x16x32_f16(W[3], a3, accA, 0, 0, 0); \
        accB = __builtin_amdgcn_mfma_f32_16x16x32_f16(W[8], b3, accB, 0, 0, 0); \
        accA = __builtin_amdgcn_mfma_f32_16x16x32_f16(W[4], a4, accA, 0, 0, 0); \
        accB = __builtin_amdgcn_mfma_f32_16x16x32_f16(W[9], b4, accB, 0, 0, 0); \
        if (xok && gy < 252) {                                                  \
            f32x4 acc = accA + accB;                                            \
            op0[0 * 63504 + yoff] = acc[0];                                     \
            op0[1 * 63504 + yoff] = acc[1];                                     \
            op0[2 * 63504 + yoff] = acc[2];                                     \
            op0[3 * 63504 + yoff] = acc[3];                                     \
        }                                                                       \
        ++gy; yoff += 252;                                                      \
    }

    #pragma unroll 1
    for (int t = 0; t < 4; ++t) {          // strip-step: waves cover x[64t,64t+63]
        const int gx = 64 * t + 16 * wv + nn;
        const bool xok = gx < 252;
        const int baseA = iiA * PLANE_DW + (gx >> 1);
        // prologue: rows 0..4 of ranges A (plane iiA) and B (plane iiA+1)
        f16x8 A0 = loadf(baseA + 0 * PITCH_DW), A1 = loadf(baseA + 1 * PITCH_DW),
              A2 = loadf(baseA + 2 * PITCH_DW), A3 = loadf(baseA + 3 * PITCH_DW),
              A4 = loadf(baseA + 4 * PITCH_DW);
        f16x8 B0 = loadf(baseA + PLANE_DW + 0 * PITCH_DW), B1 = loadf(baseA + PLANE_DW + 1 * PITCH_DW),
              B2 = loadf(baseA + PLANE_DW + 2 * PITCH_DW), B3 = loadf(baseA + PLANE_DW + 3 * PITCH_DW),
              B4 = loadf(baseA + PLANE_DW + 4 * PITCH_DW);
        int aN = baseA + 5 * PITCH_DW;

        float* const op0 = out + (size_t)n * 16 * 63504 + (size_t)(kb * 4) * 63504 + gx;
        int yoff = Y0 * 252;
        int gy = Y0;

        PHASE(A0, A1, A2, A3, A4, B0, B1, B2, B3, B4)
        PHASE(A1, A2, A3, A4, A0, B1, B2, B3, B4, B0)
        PHASE(A2, A3, A4, A0, A1, B2, B3, B4, B0, B1)
        PHASE(A3, A4, A0, A1, A2, B3, B4, B0, B1, B2)
        PHASE(A4, A0, A1, A2, A3, B4, B0, B1, B2, B3)
        PHASE(A0, A1, A2, A3, A4, B0, B1, B2, B3, B4)
        PHASE(A1, A2, A3, A4, A0, B1, B2, B3, B4, B0)
        PHASE(A2, A3, A4, A0, A1, B2, B3, B4, B0, B1)
    }
#undef PHASE
}

extern "C" void kernel_launch(void* const* d_in, const int* in_sizes, int n_in,
                              void* d_out, int out_size, void* d_ws, size_t ws_size,
                              hipStream_t stream) {
    const float* x    = (const float*)d_in[0];  // (64,6,256,256)
    const float* w    = (const float*)d_in[1];  // (10,6,5,5)
    const float* bias = (const float*)d_in[2];  // (1,16,1,1)
    float* out = (float*)d_out;                 // (64,16,252,252)
    unsigned short* Wp = (unsigned short*)d_ws; // 5120 halves (10 KB) A panel

    hipLaunchKernelGGL(prep_A, dim3(20), dim3(256), 0, stream, w, Wp);
    hipLaunchKernelGGL(c3_mfma, dim3(2048), dim3(256), 0, stream, x, Wp, bias, out);
}